// Round 2
// baseline (102.328 us; speedup 1.0000x reference)
//
#include <hip/hip_runtime.h>

// PNNLayer — exact reference semantics:
//   self_feature[n,a,:] = embeds[(32n + a) mod 50000]   (tile/reshape scramble!)
//   out[n,k] = b[k] + (1/32)Σ_a dists[a,n]·(emb[aid[a]]·W1[k,:])
//            + (1/32)Σ_a emb[(32n+a)%N]·W2[k,:]
// Since 32n mod 50000 = 16·((2n) mod 3125), the self term takes only 3125
// distinct values → precompute SBW[i,k]; main kernel is a 32-long matvec + lookup.

constexpr int N_PTS  = 50000;
constexpr int A_ANCH = 32;
constexpr int D_DIM  = 64;
constexpr int NSB    = 3125;             // distinct self-feature blocks
constexpr int TN     = 16;               // n-rows per tile (main)
constexpr int TILES  = N_PTS / TN;       // 3125
constexpr int XSTR   = 36;               // 32 + 4 pad, keeps float4 alignment
constexpr int PREP_TILE   = 16;          // i's per prep block
constexpr int PREP_BLOCKS = (NSB + PREP_TILE - 1) / PREP_TILE;   // 196

// ---- prep: blocks 0..195 -> SBW tile; block 196 -> M1 ----
__global__ __launch_bounds__(256) void prep_kernel(
        const float* __restrict__ embeds,
        const int*   __restrict__ aid,
        const float* __restrict__ W,      // (64,128)
        float*       __restrict__ M1,     // (32,64)
        float*       __restrict__ SBW)    // (3125,64)
{
    const int t = threadIdx.x;

    if (blockIdx.x == PREP_BLOCKS) {
        // M1[a,k] = (1/32) * Σ_d embeds[aid[a],d] * W[k*128 + d]
        for (int idx = t; idx < A_ANCH * D_DIM; idx += 256) {
            int a = idx >> 6, k = idx & 63;
            const float* erow = embeds + (size_t)aid[a] * D_DIM;   // broadcast in-wave
            const float* wrow = W + (size_t)k * 128;
            float s = 0.0f;
#pragma unroll
            for (int d = 0; d < D_DIM; ++d) s += erow[d] * wrow[d];
            M1[idx] = s * (1.0f / 32.0f);
        }
        return;
    }

    __shared__ float w2[64 * 64];          // w2[d*64+k] = W[k*128+64+d]
    __shared__ float sb[PREP_TILE * 64];   // sb[il*64+d]

    {   // stage W2^T; per-instr writes are 64 contiguous floats (conflict-free)
        int k  = t & 63;
        int d0 = (t >> 6) * 16;
        const float* wr = W + (size_t)k * 128 + 64;
#pragma unroll
        for (int q = 0; q < 16; ++q) w2[(d0 + q) * 64 + k] = wr[d0 + q];
    }

    const int i0 = blockIdx.x * PREP_TILE;
    {   // block sums: sb[il,d] = Σ_j embeds[(16(i0+il)+j) % N, d]; rows coalesced 256B
        int d = t & 63, il0 = t >> 6;
        for (int il = il0; il < PREP_TILE; il += 4) {
            int i = i0 + il;
            if (i >= NSB) break;           // i increases with il -> break safe
            int base = 16 * i;
            float s = 0.0f;
#pragma unroll
            for (int j = 0; j < 32; ++j) {
                int r = base + j;
                if (r >= N_PTS) r -= N_PTS;
                s += embeds[(size_t)r * D_DIM + d];
            }
            sb[il * 64 + d] = s;
        }
    }
    __syncthreads();
    {   // SBW[i,k] = (1/32) Σ_d sb[il,d]*w2[d,k]; sb reads broadcast, w2 reads contiguous
        int k = t & 63, il0 = t >> 6;
        for (int il = il0; il < PREP_TILE; il += 4) {
            int i = i0 + il;
            if (i >= NSB) break;
            const float* srow = sb + il * 64;
            float s = 0.0f;
#pragma unroll
            for (int d = 0; d < D_DIM; ++d) s += srow[d] * w2[d * 64 + k];
            SBW[(size_t)i * 64 + k] = s * (1.0f / 32.0f);
        }
    }
}

// ---- main: out[n,k] = b[k] + Σ_a dists[a,n]·M1[a,k] + SBW[(2n)%3125, k] ----
// lane map: t&15 -> k-quad (k0=4*(t&15)), t>>4 -> n_local (4 n x 16 kq per wave)
__global__ __launch_bounds__(256, 4) void pnn_main(
        const float* __restrict__ dists,   // (32, N)
        const float* __restrict__ b,       // (64,)
        const float* __restrict__ M1,      // (32,64)
        const float* __restrict__ SBW,     // (3125,64)
        float*       __restrict__ out)     // (N,64)
{
    __shared__ float m1s[A_ANCH * D_DIM];  // 8 KB
    __shared__ float xs[TN * XSTR];        // dists tile

    const int t = threadIdx.x;

    {   // stage M1: 512 float4, 2/thread, coalesced
        const float4* M4 = (const float4*)M1;
        float4*       s4 = (float4*)m1s;
#pragma unroll
        for (int q = 0; q < 2; ++q) s4[t + 256 * q] = M4[t + 256 * q];
    }

    const int lane_k  = t & 15;
    const int n_local = t >> 4;
    const int k0      = lane_k * 4;
    const float4 bias = *(const float4*)(b + k0);

    for (int tile = blockIdx.x; tile < TILES; tile += gridDim.x) {
        const int n0 = tile * TN;
        const int n  = n0 + n_local;
        const int i  = (2 * n) % NSB;                       // magic-mul, cheap
        float4 sbw = *(const float4*)(SBW + (size_t)i * D_DIM + k0);  // issue early; L2-resident

        __syncthreads();   // xs reuse guard (covers m1s staging on first pass)
        // stage dists columns: xs[nl*XSTR + a] = dists[a*N + n0+nl]; 512 vals, 2/thread
        for (int q = t; q < A_ANCH * TN; q += 256) {
            int a  = q >> 4;
            int nl = q & 15;
            xs[nl * XSTR + a] = dists[(size_t)a * N_PTS + n0 + nl];
        }
        __syncthreads();

        float4 acc;
        acc.x = bias.x + sbw.x; acc.y = bias.y + sbw.y;
        acc.z = bias.z + sbw.z; acc.w = bias.w + sbw.w;

        const float* xrow = xs + n_local * XSTR;
#pragma unroll
        for (int jj = 0; jj < A_ANCH; jj += 4) {
            float4 xv = *(const float4*)(xrow + jj);
            float4 w0 = *(const float4*)(m1s + (jj + 0) * 64 + k0);
            float4 w1 = *(const float4*)(m1s + (jj + 1) * 64 + k0);
            float4 w2 = *(const float4*)(m1s + (jj + 2) * 64 + k0);
            float4 w3 = *(const float4*)(m1s + (jj + 3) * 64 + k0);
            acc.x += xv.x * w0.x; acc.y += xv.x * w0.y; acc.z += xv.x * w0.z; acc.w += xv.x * w0.w;
            acc.x += xv.y * w1.x; acc.y += xv.y * w1.y; acc.z += xv.y * w1.z; acc.w += xv.y * w1.w;
            acc.x += xv.z * w2.x; acc.y += xv.z * w2.y; acc.z += xv.z * w2.z; acc.w += xv.z * w2.w;
            acc.x += xv.w * w3.x; acc.y += xv.w * w3.y; acc.z += xv.w * w3.z; acc.w += xv.w * w3.w;
        }
        *(float4*)(out + (size_t)n * D_DIM + k0) = acc;
    }
}

extern "C" void kernel_launch(void* const* d_in, const int* in_sizes, int n_in,
                              void* d_out, int out_size, void* d_ws, size_t ws_size,
                              hipStream_t stream) {
    const float* embeds = (const float*)d_in[0];   // (N, 64)
    const float* dists  = (const float*)d_in[1];   // (32, N)
    const int*   aid    = (const int*)  d_in[2];   // (32,)
    const float* W      = (const float*)d_in[3];   // (64, 128)
    const float* b      = (const float*)d_in[4];   // (64,)
    float*       out    = (float*)d_out;

    float* M1  = (float*)d_ws;                     // 2048 floats (8 KB)
    float* SBW = (float*)d_ws + A_ANCH * D_DIM;    // 3125*64 floats (800 KB)

    prep_kernel<<<PREP_BLOCKS + 1, 256, 0, stream>>>(embeds, aid, W, M1, SBW);
    pnn_main<<<782, 256, 0, stream>>>(dists, b, M1, SBW, out);
}